// Round 4
// baseline (460.230 us; speedup 1.0000x reference)
//
#include <hip/hip_runtime.h>
#include <hip/hip_bf16.h>
#include <math.h>

typedef __attribute__((ext_vector_type(8))) short short8;
typedef __attribute__((ext_vector_type(4))) float f32x4;

#define KDIM 150528
#define NT_TILES 20
#define KCHUNKS 24
#define STEPS 196         // 6272 / 32
#define BK 32
#define HDIM 1280
#define MDIM 256
#define PSTRIDE (MDIM * HDIM)

// packed fp32x2 -> bf16x2 RNE, single HW instruction (no builtin on gfx950)
__device__ __forceinline__ uint2 pk4(f32x4 v) {
  uint2 r;
  asm("v_cvt_pk_bf16_f32 %0, %2, %3\n\t"
      "v_cvt_pk_bf16_f32 %1, %4, %5"
      : "=&v"(r.x), "=&v"(r.y)
      : "v"(v.x), "v"(v.y), "v"(v.z), "v"(v.w));
  return r;
}

// ---------------------------------------------------------------------------
// K1: split-K GEMM  P[kc][m][n] += X[m,k]*W[n,k] over k-chunk kc.
// Tile 256x64, BK=32: W (the 770 MB matrix) has exactly ONE reader per byte
// -> W HBM traffic is drift-independent. W loads are non-temporal so L2/L3
// stay dedicated to X (154 MB, L3-resident). 512 thr, 8 waves (4m x 2n,
// wave tile 64x32), 40 KB LDS dbuf -> 2 blocks/CU, ~100 VGPR -> 4 waves/SIMD.
// ---------------------------------------------------------------------------
__global__ __launch_bounds__(512, 4) void k_gemm(
    const float* __restrict__ X, const float* __restrict__ W,
    float* __restrict__ P) {
  extern __shared__ char smem[];
  // XCD-chunked swizzle (480 % 8 == 0): each XCD owns 3 kc x 20 nt blocks,
  // so the 20 sharers of an X step-slice sit on one XCD's L2.
  const int swz = (blockIdx.x & 7) * 60 + (blockIdx.x >> 3);
  const int kc = swz / 20;
  const int nt = swz % 20;
  const long k0 = (long)kc * (BK * STEPS);

  const int tid = threadIdx.x;
  const int srow = tid >> 3;                 // 0..63
  const int scol = (tid & 7) << 2;           // float col 0..28
  const float* xA = X + (long)srow * KDIM + k0 + scol;
  const float* wB = W + (long)(nt * 64 + srow) * KDIM + k0 + scol;
  // LDS rows are 32 bf16 = 64 B; XOR bits 4-5 with row&3 for bank spread
  const int wbyte = ((tid & 7) << 3) ^ ((srow & 3) << 4);

  const int lane = tid & 63;
  const int wv = tid >> 6;                   // 0..7 -> 4m x 2n wave grid
  const int wm = wv >> 1, wn = wv & 1;
  const int frow = lane & 15;
  const int fcol = (((lane >> 4) << 4) ^ ((frow & 3) << 4));

  f32x4 acc[4][2];
#pragma unroll
  for (int i = 0; i < 4; ++i)
#pragma unroll
    for (int j = 0; j < 2; ++j) acc[i][j] = (f32x4){0.f, 0.f, 0.f, 0.f};

  f32x4 av[4], bv;
#pragma unroll
  for (int i = 0; i < 4; ++i) av[i] = *(const f32x4*)(xA + (long)(i * 64) * KDIM);
  bv = __builtin_nontemporal_load((const f32x4*)wB);
  {
    char* A = smem;
    char* B = smem + 16384;
#pragma unroll
    for (int i = 0; i < 4; ++i)
      *(uint2*)(A + (srow + i * 64) * 64 + wbyte) = pk4(av[i]);
    *(uint2*)(B + srow * 64 + wbyte) = pk4(bv);
  }
  __syncthreads();

  for (int t = 0; t < STEPS; ++t) {
    const int cur = t & 1;
    const bool has = (t + 1 < STEPS);
    if (has) {  // issue next step's loads early (hide under MFMA + TLP)
      const long off = (long)(t + 1) * BK;
#pragma unroll
      for (int i = 0; i < 4; ++i)
        av[i] = *(const f32x4*)(xA + (long)(i * 64) * KDIM + off);
      bv = __builtin_nontemporal_load((const f32x4*)(wB + off));
    }
    const char* A = smem + cur * 20480;
    const char* B = A + 16384;
    short8 fa[4], fb[2];
#pragma unroll
    for (int i = 0; i < 4; ++i)
      fa[i] = *(const short8*)(A + (wm * 64 + i * 16 + frow) * 64 + fcol);
#pragma unroll
    for (int j = 0; j < 2; ++j)
      fb[j] = *(const short8*)(B + (wn * 32 + j * 16 + frow) * 64 + fcol);
#pragma unroll
    for (int i = 0; i < 4; ++i)
#pragma unroll
      for (int j = 0; j < 2; ++j)
        acc[i][j] = __builtin_amdgcn_mfma_f32_16x16x32_bf16(fa[i], fb[j],
                                                            acc[i][j], 0, 0, 0);
    if (has) {  // convert + write next buffer (write-late)
      char* An = smem + (cur ^ 1) * 20480;
      char* Bn = An + 16384;
#pragma unroll
      for (int i = 0; i < 4; ++i)
        *(uint2*)(An + (srow + i * 64) * 64 + wbyte) = pk4(av[i]);
      *(uint2*)(Bn + srow * 64 + wbyte) = pk4(bv);
    }
    __syncthreads();
  }

  // C/D layout: col=lane&15, row=(lane>>4)*4+r  [m89]
  float* Pc = P + (long)kc * PSTRIDE + nt * 64;
  const int rb = wm * 64 + ((lane >> 4) << 2);
  const int cb = wn * 32 + frow;
#pragma unroll
  for (int i = 0; i < 4; ++i)
#pragma unroll
    for (int j = 0; j < 2; ++j) {
      const int col = cb + j * 16;
#pragma unroll
      for (int r = 0; r < 4; ++r)
        Pc[(long)(rb + i * 16 + r) * HDIM + col] = acc[i][j][r];
    }
}

// ---------------------------------------------------------------------------
// K2: S4D kernel table, one thread per (h,l).
// ---------------------------------------------------------------------------
__global__ __launch_bounds__(256) void k_s4d(
    const float* __restrict__ log_dt, const float* __restrict__ lar,
    const float* __restrict__ C, float* __restrict__ ktab) {
  const int idx = blockIdx.x * 256 + threadIdx.x;  // 1280*64
  const int h = idx >> 6, l = idx & 63;
  const float dt = expf(log_dt[h]);
  const float fl = (float)l;
  float acc = 0.f;
#pragma unroll 4
  for (int n = 0; n < 32; ++n) {
    const float A = -expf(lar[h * 32 + n]);
    const float dtA = A * dt;
    const float Cb = C[h * 32 + n] * expm1f(dtA) / A;
    acc += Cb * expf(dtA * fl);
  }
  ktab[idx] = 2.f * acc;
}

// ---------------------------------------------------------------------------
// K3: split-K reduce  U[m][h] = bb[h] + sum_kc P  (full-chip parallel)
// ---------------------------------------------------------------------------
__global__ __launch_bounds__(256) void k_red(
    const float* __restrict__ P, const float* __restrict__ bb,
    float* __restrict__ U) {
  const int idx = blockIdx.x * 256 + threadIdx.x;  // 256*1280
  float s = bb[idx % HDIM];
#pragma unroll
  for (int c = 0; c < KCHUNKS; ++c) s += P[(long)c * PSTRIDE + idx];
  U[idx] = s;
}

// ---------------------------------------------------------------------------
// K4: causal conv at l=63 + D skip + exact GELU (reads tiny U)
// ---------------------------------------------------------------------------
__global__ __launch_bounds__(256) void k_conv(
    const float* __restrict__ U, const float* __restrict__ ktab,
    const float* __restrict__ Dv, float* __restrict__ y63) {
  __shared__ float kt[64 * 65];
  const int t = threadIdx.x;
  const int hw = blockIdx.x * 64;
  for (int i = t; i < 4096; i += 256)
    kt[(i >> 6) * 65 + (i & 63)] = ktab[(hw + (i >> 6)) * 64 + (i & 63)];
  __syncthreads();
  const int hl = t & 63, b = t >> 6;
  const int h = hw + hl;
  float y = 0.f;
  for (int m = 0; m < 64; ++m)
    y += U[(long)(b * 64 + m) * HDIM + h] * kt[hl * 65 + (63 - m)];
  y += Dv[h] * U[(long)(b * 64 + 63) * HDIM + h];
  y63[b * HDIM + h] = 0.5f * y * (1.f + erff(y * 0.70710678118654752f));
}

// ---------------------------------------------------------------------------
// K5: gating z=Wc@y63+bc, last = a*sigmoid(g). One wave per h-row.
// ---------------------------------------------------------------------------
__global__ __launch_bounds__(64) void k_gate(
    const float* __restrict__ y63, const float* __restrict__ Wc,
    const float* __restrict__ bc, float* __restrict__ lastv) {
  const int r = blockIdx.x;       // 0..1279
  const int l = threadIdx.x;      // 0..63
  const float* wa = Wc + (long)r * HDIM;
  const float* wg = Wc + (long)(HDIM + r) * HDIM;
  float sa[4] = {0.f, 0.f, 0.f, 0.f}, sg[4] = {0.f, 0.f, 0.f, 0.f};
#pragma unroll
  for (int seg = 0; seg < 5; ++seg) {
    const int j = seg * 256 + l * 4;
    const f32x4 a4 = *(const f32x4*)(wa + j);
    const f32x4 g4 = *(const f32x4*)(wg + j);
#pragma unroll
    for (int b = 0; b < 4; ++b) {
      const f32x4 yv = *(const f32x4*)(y63 + b * HDIM + j);
      sa[b] += a4.x * yv.x + a4.y * yv.y + a4.z * yv.z + a4.w * yv.w;
      sg[b] += g4.x * yv.x + g4.y * yv.y + g4.z * yv.z + g4.w * yv.w;
    }
  }
#pragma unroll
  for (int off = 32; off; off >>= 1)
#pragma unroll
    for (int b = 0; b < 4; ++b) {
      sa[b] += __shfl_down(sa[b], off);
      sg[b] += __shfl_down(sg[b], off);
    }
  if (l == 0) {
    const float ba = bc[r], bg = bc[HDIM + r];
#pragma unroll
    for (int b = 0; b < 4; ++b) {
      const float za = ba + sa[b], zg = bg + sg[b];
      lastv[b * HDIM + r] = za / (1.f + expf(-zg));
    }
  }
}

// ---------------------------------------------------------------------------
// K6: head  h1 = relu(last @ W1^T + b1); out = h1 @ W2^T + b2
// ---------------------------------------------------------------------------
__global__ __launch_bounds__(64) void k_head(
    const float* __restrict__ lastv, const float* __restrict__ W1,
    const float* __restrict__ b1, const float* __restrict__ W2,
    const float* __restrict__ b2, float* __restrict__ out) {
  __shared__ float ll[HDIM];
  __shared__ float h1[64];
  const int b = blockIdx.x, t = threadIdx.x;
  for (int i = t; i < HDIM; i += 64) ll[i] = lastv[b * HDIM + i];
  __syncthreads();
  {
    const float* w = W1 + t * HDIM;
    float s = b1[t];
    for (int j = 0; j < HDIM; j += 4) {
      const f32x4 wv = *(const f32x4*)(w + j);
      s += wv.x * ll[j] + wv.y * ll[j + 1] + wv.z * ll[j + 2] + wv.w * ll[j + 3];
    }
    h1[t] = fmaxf(s, 0.f);
  }
  __syncthreads();
  if (t < 60) {
    const float* w = W2 + t * 64;
    float o = b2[t];
#pragma unroll
    for (int r = 0; r < 64; ++r) o += w[r] * h1[r];
    out[b * 60 + t] = o;
  }
}

extern "C" void kernel_launch(void* const* d_in, const int* in_sizes, int n_in,
                              void* d_out, int out_size, void* d_ws, size_t ws_size,
                              hipStream_t stream) {
  const float* x   = (const float*)d_in[0];
  const float* Wb  = (const float*)d_in[1];
  const float* bb  = (const float*)d_in[2];
  const float* ldt = (const float*)d_in[3];
  const float* C   = (const float*)d_in[4];
  const float* lar = (const float*)d_in[5];
  const float* Dv  = (const float*)d_in[6];
  const float* Wc  = (const float*)d_in[7];
  const float* bc  = (const float*)d_in[8];
  const float* W1  = (const float*)d_in[9];
  const float* b1  = (const float*)d_in[10];
  const float* W2  = (const float*)d_in[11];
  const float* b2  = (const float*)d_in[12];
  float* out = (float*)d_out;

  float* P     = (float*)d_ws;                     // 24*256*1280 f32 = 31.5 MB
  float* ktab  = P + (long)KCHUNKS * PSTRIDE;      // 1280*64
  float* U     = ktab + HDIM * 64;                 // 256*1280
  float* y63   = U + PSTRIDE;                      // 4*1280
  float* lastv = y63 + 4 * HDIM;                   // 4*1280

  (void)hipFuncSetAttribute(reinterpret_cast<const void*>(k_gemm),
                            hipFuncAttributeMaxDynamicSharedMemorySize, 40960);

  k_s4d<<<320, 256, 0, stream>>>(ldt, lar, C, ktab);
  k_gemm<<<NT_TILES * KCHUNKS, 512, 40960, stream>>>(x, Wb, P);
  k_red<<<PSTRIDE / 256, 256, 0, stream>>>(P, bb, U);
  k_conv<<<20, 256, 0, stream>>>(U, ktab, Dv, y63);
  k_gate<<<HDIM, 64, 0, stream>>>(y63, Wc, bc, lastv);
  k_head<<<4, 64, 0, stream>>>(lastv, W1, b1, W2, b2, out);
}

// Round 5
// 377.173 us; speedup vs baseline: 1.2202x; 1.2202x over previous
//
#include <hip/hip_runtime.h>
#include <hip/hip_bf16.h>
#include <math.h>

typedef __attribute__((ext_vector_type(8))) short short8;
typedef __attribute__((ext_vector_type(4))) float f32x4;

#define KDIM 150528
#define NT_TILES 20
#define KCHUNKS 24
#define STEPS 196         // 6272 / 32
#define BK 32
#define HDIM 1280
#define MDIM 256
#define PSTRIDE (MDIM * HDIM)

// packed fp32x2 -> bf16x2 RNE, single HW instruction (no builtin on gfx950)
__device__ __forceinline__ uint2 pk4(f32x4 v) {
  uint2 r;
  asm("v_cvt_pk_bf16_f32 %0, %2, %3\n\t"
      "v_cvt_pk_bf16_f32 %1, %4, %5"
      : "=&v"(r.x), "=&v"(r.y)
      : "v"(v.x), "v"(v.y), "v"(v.z), "v"(v.w));
  return r;
}

// ---------------------------------------------------------------------------
// K1: split-K GEMM  P[kc][m][n] += X[m,k]*W[n,k] over k-chunk kc.
// Tile 256x64, BK=32, 512 thr (8 waves 4m x 2n, wave tile 64x32), dbuf LDS.
// DEPTH-2 PIPELINE: loads for step t+2 issued at step t (two named reg sets,
// unroll-by-2) -> load->ds_write gap is a FULL step, hiding ~900cy HBM
// latency that R4's depth-1 structure exposed every step (3us/step, HBM 10%).
// W loads non-temporal (single reader per byte); X shared via L2/L3.
// ---------------------------------------------------------------------------
__global__ __launch_bounds__(512, 4) void k_gemm(
    const float* __restrict__ X, const float* __restrict__ W,
    float* __restrict__ P) {
  extern __shared__ char smem[];
  // XCD-chunked swizzle (480 % 8 == 0): each XCD owns 3 kc x 20 nt blocks,
  // so the 20 sharers of an X step-slice sit on one XCD's L2.
  const int swz = (blockIdx.x & 7) * 60 + (blockIdx.x >> 3);
  const int kc = swz / 20;
  const int nt = swz % 20;
  const long k0 = (long)kc * (BK * STEPS);

  const int tid = threadIdx.x;
  const int srow = tid >> 3;                 // 0..63
  const int scol = (tid & 7) << 2;           // float col 0..28
  const float* xA = X + (long)srow * KDIM + k0 + scol;
  const float* wB = W + (long)(nt * 64 + srow) * KDIM + k0 + scol;
  // LDS rows are 32 bf16 = 64 B; XOR bits 4-5 with row&3 for bank spread
  const int wbyte = ((tid & 7) << 3) ^ ((srow & 3) << 4);

  const int lane = tid & 63;
  const int wv = tid >> 6;                   // 0..7 -> 4m x 2n wave grid
  const int wm = wv >> 1, wn = wv & 1;
  const int frow = lane & 15;
  const int fcol = (((lane >> 4) << 4) ^ ((frow & 3) << 4));

  f32x4 acc[4][2];
#pragma unroll
  for (int i = 0; i < 4; ++i)
#pragma unroll
    for (int j = 0; j < 2; ++j) acc[i][j] = (f32x4){0.f, 0.f, 0.f, 0.f};

  char* bufs[2] = {smem, smem + 20480};

  f32x4 avA[4], bvA, avB[4], bvB;

#define LOADS(av, bv, step)                                                   \
  {                                                                           \
    const long off = (long)(step)*BK;                                         \
    _Pragma("unroll") for (int i = 0; i < 4; ++i)                             \
        av[i] = *(const f32x4*)(xA + (long)(i * 64) * KDIM + off);            \
    bv = __builtin_nontemporal_load((const f32x4*)(wB + off));                \
  }

#define WRITE(buf, av, bv)                                                    \
  {                                                                           \
    char* A_ = (buf);                                                         \
    char* B_ = (buf) + 16384;                                                 \
    _Pragma("unroll") for (int i = 0; i < 4; ++i)                             \
        *(uint2*)(A_ + (srow + i * 64) * 64 + wbyte) = pk4(av[i]);            \
    *(uint2*)(B_ + srow * 64 + wbyte) = pk4(bv);                              \
  }

#define COMPUTE(buf)                                                          \
  {                                                                           \
    const char* A_ = (buf);                                                   \
    const char* B_ = (buf) + 16384;                                           \
    short8 fa[4], fb[2];                                                      \
    _Pragma("unroll") for (int i = 0; i < 4; ++i)                             \
        fa[i] = *(const short8*)(A_ + (wm * 64 + i * 16 + frow) * 64 + fcol); \
    _Pragma("unroll") for (int j = 0; j < 2; ++j)                             \
        fb[j] = *(const short8*)(B_ + (wn * 32 + j * 16 + frow) * 64 + fcol); \
    _Pragma("unroll") for (int i = 0; i < 4; ++i)                             \
        _Pragma("unroll") for (int j = 0; j < 2; ++j)                         \
            acc[i][j] = __builtin_amdgcn_mfma_f32_16x16x32_bf16(              \
                fa[i], fb[j], acc[i][j], 0, 0, 0);                            \
  }

  // prologue: loads for steps 0 and 1 in flight; stage step 0
  LOADS(avA, bvA, 0);
  LOADS(avB, bvB, 1);
  WRITE(bufs[0], avA, bvA);
  __syncthreads();

  for (int t = 0; t < STEPS; t += 2) {
    // even half: compute step t (buf0); stage t+1 from setB; issue t+2 -> setA
    if (t + 2 < STEPS) LOADS(avA, bvA, t + 2);
    COMPUTE(bufs[0]);
    WRITE(bufs[1], avB, bvB);
    __syncthreads();
    // odd half: compute step t+1 (buf1); stage t+2 from setA; issue t+3 -> setB
    if (t + 3 < STEPS) LOADS(avB, bvB, t + 3);
    COMPUTE(bufs[1]);
    if (t + 2 < STEPS) WRITE(bufs[0], avA, bvA);
    __syncthreads();
  }

#undef LOADS
#undef WRITE
#undef COMPUTE

  // C/D layout: col=lane&15, row=(lane>>4)*4+r  [m89]
  float* Pc = P + (long)kc * PSTRIDE + nt * 64;
  const int rb = wm * 64 + ((lane >> 4) << 2);
  const int cb = wn * 32 + frow;
#pragma unroll
  for (int i = 0; i < 4; ++i)
#pragma unroll
    for (int j = 0; j < 2; ++j) {
      const int col = cb + j * 16;
#pragma unroll
      for (int r = 0; r < 4; ++r)
        Pc[(long)(rb + i * 16 + r) * HDIM + col] = acc[i][j][r];
    }
}

// ---------------------------------------------------------------------------
// K2: S4D kernel table, one thread per (h,l).
// ---------------------------------------------------------------------------
__global__ __launch_bounds__(256) void k_s4d(
    const float* __restrict__ log_dt, const float* __restrict__ lar,
    const float* __restrict__ C, float* __restrict__ ktab) {
  const int idx = blockIdx.x * 256 + threadIdx.x;  // 1280*64
  const int h = idx >> 6, l = idx & 63;
  const float dt = expf(log_dt[h]);
  const float fl = (float)l;
  float acc = 0.f;
#pragma unroll 4
  for (int n = 0; n < 32; ++n) {
    const float A = -expf(lar[h * 32 + n]);
    const float dtA = A * dt;
    const float Cb = C[h * 32 + n] * expm1f(dtA) / A;
    acc += Cb * expf(dtA * fl);
  }
  ktab[idx] = 2.f * acc;
}

// ---------------------------------------------------------------------------
// K3: split-K reduce  U[m][h] = bb[h] + sum_kc P  (full-chip parallel)
// ---------------------------------------------------------------------------
__global__ __launch_bounds__(256) void k_red(
    const float* __restrict__ P, const float* __restrict__ bb,
    float* __restrict__ U) {
  const int idx = blockIdx.x * 256 + threadIdx.x;  // 256*1280
  float s = bb[idx % HDIM];
#pragma unroll
  for (int c = 0; c < KCHUNKS; ++c) s += P[(long)c * PSTRIDE + idx];
  U[idx] = s;
}

// ---------------------------------------------------------------------------
// K4: causal conv at l=63 + D skip + exact GELU (reads tiny U)
// ---------------------------------------------------------------------------
__global__ __launch_bounds__(256) void k_conv(
    const float* __restrict__ U, const float* __restrict__ ktab,
    const float* __restrict__ Dv, float* __restrict__ y63) {
  __shared__ float kt[64 * 65];
  const int t = threadIdx.x;
  const int hw = blockIdx.x * 64;
  for (int i = t; i < 4096; i += 256)
    kt[(i >> 6) * 65 + (i & 63)] = ktab[(hw + (i >> 6)) * 64 + (i & 63)];
  __syncthreads();
  const int hl = t & 63, b = t >> 6;
  const int h = hw + hl;
  float y = 0.f;
  for (int m = 0; m < 64; ++m)
    y += U[(long)(b * 64 + m) * HDIM + h] * kt[hl * 65 + (63 - m)];
  y += Dv[h] * U[(long)(b * 64 + 63) * HDIM + h];
  y63[b * HDIM + h] = 0.5f * y * (1.f + erff(y * 0.70710678118654752f));
}

// ---------------------------------------------------------------------------
// K5: gating z=Wc@y63+bc, last = a*sigmoid(g). One wave per h-row.
// ---------------------------------------------------------------------------
__global__ __launch_bounds__(64) void k_gate(
    const float* __restrict__ y63, const float* __restrict__ Wc,
    const float* __restrict__ bc, float* __restrict__ lastv) {
  const int r = blockIdx.x;       // 0..1279
  const int l = threadIdx.x;      // 0..63
  const float* wa = Wc + (long)r * HDIM;
  const float* wg = Wc + (long)(HDIM + r) * HDIM;
  float sa[4] = {0.f, 0.f, 0.f, 0.f}, sg[4] = {0.f, 0.f, 0.f, 0.f};
#pragma unroll
  for (int seg = 0; seg < 5; ++seg) {
    const int j = seg * 256 + l * 4;
    const f32x4 a4 = *(const f32x4*)(wa + j);
    const f32x4 g4 = *(const f32x4*)(wg + j);
#pragma unroll
    for (int b = 0; b < 4; ++b) {
      const f32x4 yv = *(const f32x4*)(y63 + b * HDIM + j);
      sa[b] += a4.x * yv.x + a4.y * yv.y + a4.z * yv.z + a4.w * yv.w;
      sg[b] += g4.x * yv.x + g4.y * yv.y + g4.z * yv.z + g4.w * yv.w;
    }
  }
#pragma unroll
  for (int off = 32; off; off >>= 1)
#pragma unroll
    for (int b = 0; b < 4; ++b) {
      sa[b] += __shfl_down(sa[b], off);
      sg[b] += __shfl_down(sg[b], off);
    }
  if (l == 0) {
    const float ba = bc[r], bg = bc[HDIM + r];
#pragma unroll
    for (int b = 0; b < 4; ++b) {
      const float za = ba + sa[b], zg = bg + sg[b];
      lastv[b * HDIM + r] = za / (1.f + expf(-zg));
    }
  }
}

// ---------------------------------------------------------------------------
// K6: head  h1 = relu(last @ W1^T + b1); out = h1 @ W2^T + b2
// ---------------------------------------------------------------------------
__global__ __launch_bounds__(64) void k_head(
    const float* __restrict__ lastv, const float* __restrict__ W1,
    const float* __restrict__ b1, const float* __restrict__ W2,
    const float* __restrict__ b2, float* __restrict__ out) {
  __shared__ float ll[HDIM];
  __shared__ float h1[64];
  const int b = blockIdx.x, t = threadIdx.x;
  for (int i = t; i < HDIM; i += 64) ll[i] = lastv[b * HDIM + i];
  __syncthreads();
  {
    const float* w = W1 + t * HDIM;
    float s = b1[t];
    for (int j = 0; j < HDIM; j += 4) {
      const f32x4 wv = *(const f32x4*)(w + j);
      s += wv.x * ll[j] + wv.y * ll[j + 1] + wv.z * ll[j + 2] + wv.w * ll[j + 3];
    }
    h1[t] = fmaxf(s, 0.f);
  }
  __syncthreads();
  if (t < 60) {
    const float* w = W2 + t * 64;
    float o = b2[t];
#pragma unroll
    for (int r = 0; r < 64; ++r) o += w[r] * h1[r];
    out[b * 60 + t] = o;
  }
}

extern "C" void kernel_launch(void* const* d_in, const int* in_sizes, int n_in,
                              void* d_out, int out_size, void* d_ws, size_t ws_size,
                              hipStream_t stream) {
  const float* x   = (const float*)d_in[0];
  const float* Wb  = (const float*)d_in[1];
  const float* bb  = (const float*)d_in[2];
  const float* ldt = (const float*)d_in[3];
  const float* C   = (const float*)d_in[4];
  const float* lar = (const float*)d_in[5];
  const float* Dv  = (const float*)d_in[6];
  const float* Wc  = (const float*)d_in[7];
  const float* bc  = (const float*)d_in[8];
  const float* W1  = (const float*)d_in[9];
  const float* b1  = (const float*)d_in[10];
  const float* W2  = (const float*)d_in[11];
  const float* b2  = (const float*)d_in[12];
  float* out = (float*)d_out;

  float* P     = (float*)d_ws;                     // 24*256*1280 f32 = 31.5 MB
  float* ktab  = P + (long)KCHUNKS * PSTRIDE;      // 1280*64
  float* U     = ktab + HDIM * 64;                 // 256*1280
  float* y63   = U + PSTRIDE;                      // 4*1280
  float* lastv = y63 + 4 * HDIM;                   // 4*1280

  (void)hipFuncSetAttribute(reinterpret_cast<const void*>(k_gemm),
                            hipFuncAttributeMaxDynamicSharedMemorySize, 40960);

  k_s4d<<<320, 256, 0, stream>>>(ldt, lar, C, ktab);
  k_gemm<<<NT_TILES * KCHUNKS, 512, 40960, stream>>>(x, Wb, P);
  k_red<<<PSTRIDE / 256, 256, 0, stream>>>(P, bb, U);
  k_conv<<<20, 256, 0, stream>>>(U, ktab, Dv, y63);
  k_gate<<<HDIM, 64, 0, stream>>>(y63, Wc, bc, lastv);
  k_head<<<4, 64, 0, stream>>>(lastv, W1, b1, W2, b2, out);
}